// Round 8
// baseline (679.521 us; speedup 1.0000x reference)
//
#include <hip/hip_runtime.h>
#include <hip/hip_bf16.h>

constexpr int kNB = 2, kNS = 2, kNF = 512, kNPTS = 1024;
constexpr int kNLS = 12, kNLV = 6;
constexpr int kNTGT = kNB * kNF;  // 1024

typedef float f32x4 __attribute__((ext_vector_type(4)));
typedef short bf16x8 __attribute__((ext_vector_type(8)));

// Weight-frag layout in ws: per MLP 12288 bf16: W1@0 (4 frags), W2@2048 (8),
// W3@6144 (8), Wo@10240 (4). Frag = 64 lanes x 8 bf16 = 512 elems.
// Frag element p of lane l = W[k][n], k = 32*f + 8*(l>>4) + p, n = 16*ct + (l&15).
// Biases in ws: per MLP 224 f32: b1@0, b2@64, b3@128, bo@192 (padded).
constexpr int kWperMLP = 12288;
constexpr int kBperMLP = 224;

__device__ __forceinline__ unsigned short f2bf(float x) {
  union { float f; unsigned u; } v;
  v.f = x;
  unsigned r = v.u + 0x7fffu + ((v.u >> 16) & 1u);
  return (unsigned short)(r >> 16);
}
__device__ __forceinline__ float bf2f(short b) {
  union { unsigned u; float f; } v;
  v.u = ((unsigned)(unsigned short)b) << 16;
  return v.f;
}
// Native f32->bf16 via the ROCm bf16 API (verified working/pass in R7).
// a -> low 16 bits, b -> high 16 bits.
__device__ __forceinline__ unsigned pk2(float a, float b) {
  union { __hip_bfloat162 h2; unsigned u; } cv;
  cv.h2.x = __float2bfloat16(a);
  cv.h2.y = __float2bfloat16(b);
  return cv.u;
}
__device__ __forceinline__ float silu_f(float t) {
  return t * __builtin_amdgcn_rcpf(1.0f + __expf(-t));
}
__device__ __forceinline__ float wred64(float v) {
#pragma unroll
  for (int off = 32; off > 0; off >>= 1) v += __shfl_xor(v, off, 64);
  return v;
}

__global__ void prep_nrm(const float* __restrict__ normals,
                         float* __restrict__ nrm) {
  const int i = blockIdx.x * blockDim.x + threadIdx.x;
  if (i < kNTGT) {
    const float x = normals[i * 3 + 0], y = normals[i * 3 + 1],
                z = normals[i * 3 + 2];
    const float inv = rsqrtf(x * x + y * y + z * z);
    nrm[i * 3 + 0] = x * inv;
    nrm[i * 3 + 1] = y * inv;
    nrm[i * 3 + 2] = z * inv;
  }
}

// Gather weights (KR x NR row-major, fp32) into frag-direct bf16 layout.
template <int KR, int NR, int KP, int NP>
__global__ void prep_w(const float* __restrict__ src, short* __restrict__ dst,
                       int woff, int nmats, int mlp0) {
  constexpr int NCT = NP / 16, NF = KP / 32, NFRAG = NCT * NF;
  const int i = blockIdx.x * blockDim.x + threadIdx.x;
  if (i >= nmats * NFRAG * 64) return;
  const int lane = i & 63;
  const int frag = (i >> 6) % NFRAG;
  const int mat = i / (64 * NFRAG);
  const int ct = frag / NF, f = frag % NF;
  const int k0 = 32 * f + 8 * (lane >> 4);
  const int n = 16 * ct + (lane & 15);
  bf16x8 o;
#pragma unroll
  for (int p = 0; p < 8; ++p) {
    const int k = k0 + p;
    const float v = (k < KR && n < NR) ? src[(mat * KR + k) * NR + n] : 0.f;
    o[p] = (short)f2bf(v);
  }
  *(bf16x8*)(dst + (long)(mlp0 + mat) * kWperMLP + woff + frag * 512 +
             lane * 8) = o;
}

__global__ void prep_b(const float* __restrict__ src, float* __restrict__ dst,
                       int nmats, int NRr, int NPp, int off, int mlp0) {
  const int i = blockIdx.x * blockDim.x + threadIdx.x;
  if (i >= nmats * NPp) return;
  const int mat = i / NPp, j = i % NPp;
  dst[(mlp0 + mat) * kBperMLP + off + j] = (j < NRr) ? src[mat * NRr + j] : 0.f;
}

// Main fused kernel. One block per target; 4 waves x 64; wave owns 64 rows;
// two 256-row halves per combo (LDS halved -> 3 blocks/CU). All LDS traffic
// is wave-private (rows <-> waves aligned) => no barriers in the combo loop.
template <bool FIRST, bool FINAL>
__global__ __launch_bounds__(256, 3) void mlp_main(
    const float* __restrict__ tgt, const float* __restrict__ cent,
    const float* __restrict__ nrm, const float* __restrict__ areas,
    const float* __restrict__ refl, const short* __restrict__ WL,
    const float* __restrict__ BL, int mlp0, const float* __restrict__ scal_in,
    const float* __restrict__ vecs_in, float* __restrict__ scal_out,
    float* __restrict__ vecs_out, const float* __restrict__ calib,
    float* __restrict__ out4) {
  __shared__ short Xb[256 * 32];  // features / out staging, swz ^((m&3)<<4)
  __shared__ short Hb[256 * 64];  // hidden activations, swz ^((m&7)<<4)
  __shared__ float red[4 * 32];
  char* Xc = (char*)Xb;
  char* Hc = (char*)Hb;
  const int tid = threadIdx.x;
  const int lane = tid & 63;
  const int c15 = lane & 15, q = lane >> 4;
  const int wave = tid >> 6;
  const int t = blockIdx.x;
  const float tx = tgt[t * 3 + 0], ty = tgt[t * 3 + 1], tz = tgt[t * 3 + 2];
  const int m = tid;               // this thread's local row (0..255)
  const int mf = wave * 64 + c15;  // frag-read row base (+ rt*16)

  constexpr int NACC = FINAL ? 4 : 30;
  float acc[NACC];
#pragma unroll
  for (int k = 0; k < NACC; ++k) acc[k] = 0.f;

#pragma unroll 1
  for (int bs = 0; bs < 4; ++bs) {
    const int b = bs >> 1, s = bs & 1;
    const short* wb = WL + (long)(mlp0 + bs) * kWperMLP;
    const float* bb = BL + (mlp0 + bs) * kBperMLP;

#pragma unroll 1
    for (int half = 0; half < 2; ++half) {
      // ---------- features for row m of this half ----------
      const int sg = b * kNF + half * 256 + m;
      const float px = cent[sg * 3 + 0], py = cent[sg * 3 + 1],
                  pz = cent[sg * 3 + 2];
      const float nx = nrm[sg * 3 + 0], ny = nrm[sg * 3 + 1],
                  nz = nrm[sg * 3 + 2];
      const float wgt = areas[sg];
      const float rvx = tx - px, rvy = ty - py, rvz = tz - pz;
      const float r = sqrtf(rvx * rvx + rvy * rvy + rvz * rvz + 1e-16f);
      const float rinv = 1.f / r;
      const float rhx = rvx * rinv, rhy = rvy * rinv, rhz = rvz * rinv;
      const float cth = rhx * nx + rhy * ny + rhz * nz;
      {
        float f[32];
        f[0] = __logf(r / refl[s]);
        f[1] = 1.f;
        f[2] = cth;
        f[3] = 0.5f * (3.f * cth * cth - 1.f);
        f[4] = 0.5f * cth * (5.f * cth * cth - 3.f);
        if constexpr (!FIRST) {
#pragma unroll
          for (int k = 0; k < kNLS; ++k) f[5 + k] = scal_in[sg * kNLS + k];
#pragma unroll
          for (int v = 0; v < kNLV; ++v) {
            const float vx = vecs_in[sg * 18 + v * 3 + 0];
            const float vy = vecs_in[sg * 18 + v * 3 + 1];
            const float vz = vecs_in[sg * 18 + v * 3 + 2];
            f[17 + v] = rhx * vx + rhy * vy + rhz * vz;
            f[23 + v] = nx * vx + ny * vy + nz * vz;
          }
        } else {
#pragma unroll
          for (int k = 5; k < 29; ++k) f[k] = 0.f;
        }
        f[29] = f[30] = f[31] = 0.f;
#pragma unroll
        for (int g = 0; g < 8; ++g) {
          uint2 u;
          u.x = pk2(f[4 * g + 0], f[4 * g + 1]);
          u.y = pk2(f[4 * g + 2], f[4 * g + 3]);
          *(uint2*)(Xc + ((m * 64 + 8 * g) ^ ((m & 3) << 4))) = u;
        }
      }

      // ---------- layer 1: K=32 (from Xb) ----------
      {
        bf16x8 w1[4];
        f32x4 bv[4];
#pragma unroll
        for (int ct = 0; ct < 4; ++ct) {
          w1[ct] = *(const bf16x8*)(wb + ct * 512 + lane * 8);
          bv[ct] = *(const f32x4*)(bb + 16 * ct + 4 * q);
        }
        f32x4 a[4][4];
#pragma unroll
        for (int rt = 0; rt < 4; ++rt) {
          const int mr = mf + rt * 16;
          const bf16x8 xf =
              *(const bf16x8*)(Xc + ((mr * 64 + 16 * q) ^ ((mr & 3) << 4)));
#pragma unroll
          for (int ct = 0; ct < 4; ++ct)
            a[rt][ct] = __builtin_amdgcn_mfma_f32_16x16x32_bf16(
                w1[ct], xf, bv[ct], 0, 0, 0);
        }
#pragma unroll
        for (int rt = 0; rt < 4; ++rt) {
          const int mr = mf + rt * 16;
#pragma unroll
          for (int ct = 0; ct < 4; ++ct) {
            f32x4 v = a[rt][ct];
            uint2 u;
            u.x = pk2(silu_f(v.x), silu_f(v.y));
            u.y = pk2(silu_f(v.z), silu_f(v.w));
            *(uint2*)(Hc + ((mr * 128 + 32 * ct + 8 * q) ^ ((mr & 7) << 4))) =
                u;
          }
        }
      }

      // ---------- layers 2,3: K=64, H -> H in place (wave-private) ----------
#pragma unroll 1
      for (int L = 0; L < 2; ++L) {
        const int woff = (L == 0) ? 2048 : 6144;
        const int boff = (L == 0) ? 64 : 128;
        bf16x8 w[4][2];
        f32x4 bv[4];
#pragma unroll
        for (int ct = 0; ct < 4; ++ct) {
          w[ct][0] =
              *(const bf16x8*)(wb + woff + (ct * 2 + 0) * 512 + lane * 8);
          w[ct][1] =
              *(const bf16x8*)(wb + woff + (ct * 2 + 1) * 512 + lane * 8);
          bv[ct] = *(const f32x4*)(bb + boff + 16 * ct + 4 * q);
        }
        f32x4 a[4][4];
#pragma unroll
        for (int rt = 0; rt < 4; ++rt) {
          const int mr = mf + rt * 16;
          const bf16x8 h0 =
              *(const bf16x8*)(Hc + ((mr * 128 + 16 * q) ^ ((mr & 7) << 4)));
          const bf16x8 h1 = *(const bf16x8*)(Hc + ((mr * 128 + 64 + 16 * q) ^
                                                   ((mr & 7) << 4)));
#pragma unroll
          for (int ct = 0; ct < 4; ++ct) {
            f32x4 aa = __builtin_amdgcn_mfma_f32_16x16x32_bf16(w[ct][0], h0,
                                                               bv[ct], 0, 0, 0);
            aa = __builtin_amdgcn_mfma_f32_16x16x32_bf16(w[ct][1], h1, aa, 0, 0,
                                                         0);
            a[rt][ct] = aa;
          }
        }
#pragma unroll
        for (int rt = 0; rt < 4; ++rt) {
          const int mr = mf + rt * 16;
#pragma unroll
          for (int ct = 0; ct < 4; ++ct) {
            f32x4 v = a[rt][ct];
            uint2 u;
            u.x = pk2(silu_f(v.x), silu_f(v.y));
            u.y = pk2(silu_f(v.z), silu_f(v.w));
            *(uint2*)(Hc + ((mr * 128 + 32 * ct + 8 * q) ^ ((mr & 7) << 4))) =
                u;
          }
        }
      }

      // ---------- output layer (no activation), staged into Xb ----------
      {
        constexpr int NCTO = FINAL ? 1 : 2;
        bf16x8 wo[NCTO][2];
        f32x4 bv[NCTO];
#pragma unroll
        for (int ct = 0; ct < NCTO; ++ct) {
          wo[ct][0] =
              *(const bf16x8*)(wb + 10240 + (ct * 2 + 0) * 512 + lane * 8);
          wo[ct][1] =
              *(const bf16x8*)(wb + 10240 + (ct * 2 + 1) * 512 + lane * 8);
          bv[ct] = *(const f32x4*)(bb + 192 + 16 * ct + 4 * q);
        }
#pragma unroll
        for (int rt = 0; rt < 4; ++rt) {
          const int mr = mf + rt * 16;
          const bf16x8 h0 =
              *(const bf16x8*)(Hc + ((mr * 128 + 16 * q) ^ ((mr & 7) << 4)));
          const bf16x8 h1 = *(const bf16x8*)(Hc + ((mr * 128 + 64 + 16 * q) ^
                                                   ((mr & 7) << 4)));
#pragma unroll
          for (int ct = 0; ct < NCTO; ++ct) {
            f32x4 aa = __builtin_amdgcn_mfma_f32_16x16x32_bf16(wo[ct][0], h0,
                                                               bv[ct], 0, 0, 0);
            aa = __builtin_amdgcn_mfma_f32_16x16x32_bf16(wo[ct][1], h1, aa, 0,
                                                         0, 0);
            uint2 u;
            u.x = pk2(aa.x, aa.y);
            u.y = pk2(aa.z, aa.w);
            *(uint2*)(Xc + ((mr * 64 + 32 * ct + 8 * q) ^ ((mr & 3) << 4))) = u;
          }
        }
      }

      // ---------- epilogue: thread reads row m's outputs, accumulates ------
      if constexpr (!FINAL) {
        float o[24];
#pragma unroll
        for (int j = 0; j < 3; ++j) {
          const bf16x8 v =
              *(const bf16x8*)(Xc + ((m * 64 + 16 * j) ^ ((m & 3) << 4)));
#pragma unroll
          for (int i = 0; i < 8; ++i) o[8 * j + i] = bf2f(v[i]);
        }
#pragma unroll
        for (int k = 0; k < kNLS; ++k) acc[k] += o[k] * wgt;
#pragma unroll
        for (int v = 0; v < kNLV; ++v) {
          const float cr = o[12 + v] * wgt, cn = o[18 + v] * wgt;
          acc[12 + v * 3 + 0] += cr * rhx + cn * nx;
          acc[12 + v * 3 + 1] += cr * rhy + cn * ny;
          acc[12 + v * 3 + 2] += cr * rhz + cn * nz;
        }
      } else {
        const bf16x8 v = *(const bf16x8*)(Xc + ((m * 64) ^ ((m & 3) << 4)));
        const float o0 = bf2f(v[0]), o1 = bf2f(v[1]), o2 = bf2f(v[2]);
        acc[0] += o0 * wgt;
        acc[1] += wgt * (o1 * rhx + o2 * nx);
        acc[2] += wgt * (o1 * rhy + o2 * ny);
        acc[3] += wgt * (o1 * rhz + o2 * nz);
      }
    }  // half
  }    // bs

  // ---------- block reduction ----------
#pragma unroll
  for (int k = 0; k < NACC; ++k) acc[k] = wred64(acc[k]);
  if (lane == 0) {
#pragma unroll
    for (int k = 0; k < NACC; ++k) red[wave * 32 + k] = acc[k];
  }
  __syncthreads();
  if (tid < NACC) {
    float sum = 0.f;
#pragma unroll
    for (int w = 0; w < 4; ++w) sum += red[w * 32 + tid];
    if constexpr (!FINAL) {
      if (tid < kNLS)
        scal_out[t * kNLS + tid] = sum;
      else
        vecs_out[t * 18 + (tid - kNLS)] = sum;
    } else {
      const float o =
          (tid == 0) ? (calib[0] * sum + calib[1]) : (calib[2] * sum);
      out4[t * 4 + tid] = o;
    }
  }
}

extern "C" void kernel_launch(void* const* d_in, const int* in_sizes, int n_in,
                              void* d_out, int out_size, void* d_ws,
                              size_t ws_size, hipStream_t stream) {
  const float* pred = (const float*)d_in[0];
  const float* cent = (const float*)d_in[1];
  const float* normals = (const float*)d_in[2];
  const float* areas = (const float*)d_in[3];
  const float* refl = (const float*)d_in[4];
  const float* cW1 = (const float*)d_in[5];
  const float* cb1 = (const float*)d_in[6];
  const float* cW2 = (const float*)d_in[7];
  const float* cb2 = (const float*)d_in[8];
  const float* cW3 = (const float*)d_in[9];
  const float* cb3 = (const float*)d_in[10];
  const float* cWo = (const float*)d_in[11];
  const float* cbo = (const float*)d_in[12];
  const float* fW1 = (const float*)d_in[13];
  const float* fb1 = (const float*)d_in[14];
  const float* fW2 = (const float*)d_in[15];
  const float* fb2 = (const float*)d_in[16];
  const float* fW3 = (const float*)d_in[17];
  const float* fb3 = (const float*)d_in[18];
  const float* fWo = (const float*)d_in[19];
  const float* fbo = (const float*)d_in[20];
  const float* calib = (const float*)d_in[21];

  float* ws = (float*)d_ws;
  float* nrmp = ws;                   // 3072
  float* scalA = nrmp + 3072;         // 12288
  float* vecsA = scalA + 12288;       // 18432
  float* scalB = vecsA + 18432;       // 12288
  float* vecsB = scalB + 12288;       // 18432
  float* BLs = vecsB + 18432;         // 12 * 224 = 2688
  short* WLs = (short*)(BLs + 2688);  // 12 * 12288 bf16
  float* outp = (float*)d_out;

  prep_nrm<<<4, 256, 0, stream>>>(normals, nrmp);

  // weights -> frag layout (c-MLPs are mlp 0..7, f-MLPs are 8..11)
  prep_w<29, 64, 32, 64><<<8, 256, 0, stream>>>(cW1, WLs, 0, 8, 0);
  prep_w<64, 64, 64, 64><<<16, 256, 0, stream>>>(cW2, WLs, 2048, 8, 0);
  prep_w<64, 64, 64, 64><<<16, 256, 0, stream>>>(cW3, WLs, 6144, 8, 0);
  prep_w<64, 24, 64, 32><<<8, 256, 0, stream>>>(cWo, WLs, 10240, 8, 0);
  prep_w<29, 64, 32, 64><<<4, 256, 0, stream>>>(fW1, WLs, 0, 4, 8);
  prep_w<64, 64, 64, 64><<<8, 256, 0, stream>>>(fW2, WLs, 2048, 4, 8);
  prep_w<64, 64, 64, 64><<<8, 256, 0, stream>>>(fW3, WLs, 6144, 4, 8);
  prep_w<64, 3, 64, 32><<<4, 256, 0, stream>>>(fWo, WLs, 10240, 4, 8);

  prep_b<<<2, 256, 0, stream>>>(cb1, BLs, 8, 64, 64, 0, 0);
  prep_b<<<2, 256, 0, stream>>>(cb2, BLs, 8, 64, 64, 64, 0);
  prep_b<<<2, 256, 0, stream>>>(cb3, BLs, 8, 64, 64, 128, 0);
  prep_b<<<1, 256, 0, stream>>>(cbo, BLs, 8, 24, 32, 192, 0);
  prep_b<<<1, 256, 0, stream>>>(fb1, BLs, 4, 64, 64, 0, 8);
  prep_b<<<1, 256, 0, stream>>>(fb2, BLs, 4, 64, 64, 64, 8);
  prep_b<<<1, 256, 0, stream>>>(fb3, BLs, 4, 64, 64, 128, 8);
  prep_b<<<1, 256, 0, stream>>>(fbo, BLs, 4, 3, 32, 192, 8);

  mlp_main<true, false><<<kNTGT, 256, 0, stream>>>(
      cent, cent, nrmp, areas, refl, WLs, BLs, 0, nullptr, nullptr, scalA,
      vecsA, nullptr, nullptr);
  mlp_main<false, false><<<kNTGT, 256, 0, stream>>>(
      cent, cent, nrmp, areas, refl, WLs, BLs, 4, scalA, vecsA, scalB, vecsB,
      nullptr, nullptr);
  mlp_main<false, true><<<kNPTS, 256, 0, stream>>>(
      pred, cent, nrmp, areas, refl, WLs, BLs, 8, scalB, vecsB, nullptr,
      nullptr, calib, outp);
}

// Round 9
// 462.076 us; speedup vs baseline: 1.4706x; 1.4706x over previous
//
#include <hip/hip_runtime.h>
#include <hip/hip_bf16.h>

constexpr int kNB = 2, kNS = 2, kNF = 512, kNPTS = 1024;
constexpr int kNLS = 12, kNLV = 6;
constexpr int kNTGT = kNB * kNF;  // 1024

typedef float f32x4 __attribute__((ext_vector_type(4)));
typedef short bf16x8 __attribute__((ext_vector_type(8)));

// Weight-frag layout in ws: per MLP 12288 bf16: W1@0 (4 frags), W2@2048 (8),
// W3@6144 (8), Wo@10240 (4). Frag = 64 lanes x 8 bf16 = 512 elems.
// Frag element p of lane l = W[k][n], k = 32*f + 8*(l>>4) + p, n = 16*ct + (l&15).
// Biases in ws: per MLP 224 f32: b1@0, b2@64, b3@128, bo@192 (padded).
constexpr int kWperMLP = 12288;
constexpr int kBperMLP = 224;

__device__ __forceinline__ unsigned short f2bf(float x) {
  union { float f; unsigned u; } v;
  v.f = x;
  unsigned r = v.u + 0x7fffu + ((v.u >> 16) & 1u);
  return (unsigned short)(r >> 16);
}
__device__ __forceinline__ float bf2f(short b) {
  union { unsigned u; float f; } v;
  v.u = ((unsigned)(unsigned short)b) << 16;
  return v.f;
}
// Native f32->bf16 via the ROCm bf16 API (verified working/pass in R7).
// a -> low 16 bits, b -> high 16 bits.
__device__ __forceinline__ unsigned pk2(float a, float b) {
  union { __hip_bfloat162 h2; unsigned u; } cv;
  cv.h2.x = __float2bfloat16(a);
  cv.h2.y = __float2bfloat16(b);
  return cv.u;
}
__device__ __forceinline__ float silu_f(float t) {
  return t * __builtin_amdgcn_rcpf(1.0f + __expf(-t));
}
__device__ __forceinline__ float wred64(float v) {
#pragma unroll
  for (int off = 32; off > 0; off >>= 1) v += __shfl_xor(v, off, 64);
  return v;
}

__global__ void prep_nrm(const float* __restrict__ normals,
                         float* __restrict__ nrm) {
  const int i = blockIdx.x * blockDim.x + threadIdx.x;
  if (i < kNTGT) {
    const float x = normals[i * 3 + 0], y = normals[i * 3 + 1],
                z = normals[i * 3 + 2];
    const float inv = rsqrtf(x * x + y * y + z * z);
    nrm[i * 3 + 0] = x * inv;
    nrm[i * 3 + 1] = y * inv;
    nrm[i * 3 + 2] = z * inv;
  }
}

// Gather weights (KR x NR row-major, fp32) into frag-direct bf16 layout.
template <int KR, int NR, int KP, int NP>
__global__ void prep_w(const float* __restrict__ src, short* __restrict__ dst,
                       int woff, int nmats, int mlp0) {
  constexpr int NCT = NP / 16, NF = KP / 32, NFRAG = NCT * NF;
  const int i = blockIdx.x * blockDim.x + threadIdx.x;
  if (i >= nmats * NFRAG * 64) return;
  const int lane = i & 63;
  const int frag = (i >> 6) % NFRAG;
  const int mat = i / (64 * NFRAG);
  const int ct = frag / NF, f = frag % NF;
  const int k0 = 32 * f + 8 * (lane >> 4);
  const int n = 16 * ct + (lane & 15);
  bf16x8 o;
#pragma unroll
  for (int p = 0; p < 8; ++p) {
    const int k = k0 + p;
    const float v = (k < KR && n < NR) ? src[(mat * KR + k) * NR + n] : 0.f;
    o[p] = (short)f2bf(v);
  }
  *(bf16x8*)(dst + (long)(mlp0 + mat) * kWperMLP + woff + frag * 512 +
             lane * 8) = o;
}

__global__ void prep_b(const float* __restrict__ src, float* __restrict__ dst,
                       int nmats, int NRr, int NPp, int off, int mlp0) {
  const int i = blockIdx.x * blockDim.x + threadIdx.x;
  if (i >= nmats * NPp) return;
  const int mat = i / NPp, j = i % NPp;
  dst[(mlp0 + mat) * kBperMLP + off + j] = (j < NRr) ? src[mat * NRr + j] : 0.f;
}

// Main fused kernel. One block per target; 4 waves x 64; wave owns 64 rows;
// two 256-row halves per combo (LDS halved -> 3 blocks/CU, LDS-limited).
// All LDS traffic is wave-private (rows <-> waves aligned) => no barriers
// in the combo loop.
// launch_bounds(256, 2): VGPR cap 256. Do NOT raise the min-waves arg to 3 —
// the allocator can't fit the ~190-reg live set in the 170-reg tier and
// spills ~600 MB/dispatch to scratch (measured R8: VGPR 84, hbm 6.6e8).
template <bool FIRST, bool FINAL>
__global__ __launch_bounds__(256, 2) void mlp_main(
    const float* __restrict__ tgt, const float* __restrict__ cent,
    const float* __restrict__ nrm, const float* __restrict__ areas,
    const float* __restrict__ refl, const short* __restrict__ WL,
    const float* __restrict__ BL, int mlp0, const float* __restrict__ scal_in,
    const float* __restrict__ vecs_in, float* __restrict__ scal_out,
    float* __restrict__ vecs_out, const float* __restrict__ calib,
    float* __restrict__ out4) {
  __shared__ short Xb[256 * 32];  // features / out staging, swz ^((m&3)<<4)
  __shared__ short Hb[256 * 64];  // hidden activations, swz ^((m&7)<<4)
  __shared__ float red[4 * 32];
  char* Xc = (char*)Xb;
  char* Hc = (char*)Hb;
  const int tid = threadIdx.x;
  const int lane = tid & 63;
  const int c15 = lane & 15, q = lane >> 4;
  const int wave = tid >> 6;
  const int t = blockIdx.x;
  const float tx = tgt[t * 3 + 0], ty = tgt[t * 3 + 1], tz = tgt[t * 3 + 2];
  const int m = tid;               // this thread's local row (0..255)
  const int mf = wave * 64 + c15;  // frag-read row base (+ rt*16)

  constexpr int NACC = FINAL ? 4 : 30;
  float acc[NACC];
#pragma unroll
  for (int k = 0; k < NACC; ++k) acc[k] = 0.f;

#pragma unroll 1
  for (int bs = 0; bs < 4; ++bs) {
    const int b = bs >> 1, s = bs & 1;
    const short* wb = WL + (long)(mlp0 + bs) * kWperMLP;
    const float* bb = BL + (mlp0 + bs) * kBperMLP;

#pragma unroll 1
    for (int half = 0; half < 2; ++half) {
      // ---------- features for row m of this half ----------
      const int sg = b * kNF + half * 256 + m;
      const float px = cent[sg * 3 + 0], py = cent[sg * 3 + 1],
                  pz = cent[sg * 3 + 2];
      const float nx = nrm[sg * 3 + 0], ny = nrm[sg * 3 + 1],
                  nz = nrm[sg * 3 + 2];
      const float wgt = areas[sg];
      const float rvx = tx - px, rvy = ty - py, rvz = tz - pz;
      const float r = sqrtf(rvx * rvx + rvy * rvy + rvz * rvz + 1e-16f);
      const float rinv = 1.f / r;
      const float rhx = rvx * rinv, rhy = rvy * rinv, rhz = rvz * rinv;
      const float cth = rhx * nx + rhy * ny + rhz * nz;
      {
        float f[32];
        f[0] = __logf(r / refl[s]);
        f[1] = 1.f;
        f[2] = cth;
        f[3] = 0.5f * (3.f * cth * cth - 1.f);
        f[4] = 0.5f * cth * (5.f * cth * cth - 3.f);
        if constexpr (!FIRST) {
#pragma unroll
          for (int k = 0; k < kNLS; ++k) f[5 + k] = scal_in[sg * kNLS + k];
#pragma unroll
          for (int v = 0; v < kNLV; ++v) {
            const float vx = vecs_in[sg * 18 + v * 3 + 0];
            const float vy = vecs_in[sg * 18 + v * 3 + 1];
            const float vz = vecs_in[sg * 18 + v * 3 + 2];
            f[17 + v] = rhx * vx + rhy * vy + rhz * vz;
            f[23 + v] = nx * vx + ny * vy + nz * vz;
          }
        } else {
#pragma unroll
          for (int k = 5; k < 29; ++k) f[k] = 0.f;
        }
        f[29] = f[30] = f[31] = 0.f;
#pragma unroll
        for (int g = 0; g < 8; ++g) {
          uint2 u;
          u.x = pk2(f[4 * g + 0], f[4 * g + 1]);
          u.y = pk2(f[4 * g + 2], f[4 * g + 3]);
          *(uint2*)(Xc + ((m * 64 + 8 * g) ^ ((m & 3) << 4))) = u;
        }
      }

      // ---------- layer 1: K=32 (from Xb) ----------
      {
        bf16x8 w1[4];
        f32x4 bv[4];
#pragma unroll
        for (int ct = 0; ct < 4; ++ct) {
          w1[ct] = *(const bf16x8*)(wb + ct * 512 + lane * 8);
          bv[ct] = *(const f32x4*)(bb + 16 * ct + 4 * q);
        }
        f32x4 a[4][4];
#pragma unroll
        for (int rt = 0; rt < 4; ++rt) {
          const int mr = mf + rt * 16;
          const bf16x8 xf =
              *(const bf16x8*)(Xc + ((mr * 64 + 16 * q) ^ ((mr & 3) << 4)));
#pragma unroll
          for (int ct = 0; ct < 4; ++ct)
            a[rt][ct] = __builtin_amdgcn_mfma_f32_16x16x32_bf16(
                w1[ct], xf, bv[ct], 0, 0, 0);
        }
#pragma unroll
        for (int rt = 0; rt < 4; ++rt) {
          const int mr = mf + rt * 16;
#pragma unroll
          for (int ct = 0; ct < 4; ++ct) {
            f32x4 v = a[rt][ct];
            uint2 u;
            u.x = pk2(silu_f(v.x), silu_f(v.y));
            u.y = pk2(silu_f(v.z), silu_f(v.w));
            *(uint2*)(Hc + ((mr * 128 + 32 * ct + 8 * q) ^ ((mr & 7) << 4))) =
                u;
          }
        }
      }

      // ---------- layers 2,3: K=64, H -> H in place (wave-private) ----------
#pragma unroll 1
      for (int L = 0; L < 2; ++L) {
        const int woff = (L == 0) ? 2048 : 6144;
        const int boff = (L == 0) ? 64 : 128;
        bf16x8 w[4][2];
        f32x4 bv[4];
#pragma unroll
        for (int ct = 0; ct < 4; ++ct) {
          w[ct][0] =
              *(const bf16x8*)(wb + woff + (ct * 2 + 0) * 512 + lane * 8);
          w[ct][1] =
              *(const bf16x8*)(wb + woff + (ct * 2 + 1) * 512 + lane * 8);
          bv[ct] = *(const f32x4*)(bb + boff + 16 * ct + 4 * q);
        }
        f32x4 a[4][4];
#pragma unroll
        for (int rt = 0; rt < 4; ++rt) {
          const int mr = mf + rt * 16;
          const bf16x8 h0 =
              *(const bf16x8*)(Hc + ((mr * 128 + 16 * q) ^ ((mr & 7) << 4)));
          const bf16x8 h1 = *(const bf16x8*)(Hc + ((mr * 128 + 64 + 16 * q) ^
                                                   ((mr & 7) << 4)));
#pragma unroll
          for (int ct = 0; ct < 4; ++ct) {
            f32x4 aa = __builtin_amdgcn_mfma_f32_16x16x32_bf16(w[ct][0], h0,
                                                               bv[ct], 0, 0, 0);
            aa = __builtin_amdgcn_mfma_f32_16x16x32_bf16(w[ct][1], h1, aa, 0, 0,
                                                         0);
            a[rt][ct] = aa;
          }
        }
#pragma unroll
        for (int rt = 0; rt < 4; ++rt) {
          const int mr = mf + rt * 16;
#pragma unroll
          for (int ct = 0; ct < 4; ++ct) {
            f32x4 v = a[rt][ct];
            uint2 u;
            u.x = pk2(silu_f(v.x), silu_f(v.y));
            u.y = pk2(silu_f(v.z), silu_f(v.w));
            *(uint2*)(Hc + ((mr * 128 + 32 * ct + 8 * q) ^ ((mr & 7) << 4))) =
                u;
          }
        }
      }

      // ---------- output layer (no activation), staged into Xb ----------
      {
        constexpr int NCTO = FINAL ? 1 : 2;
        bf16x8 wo[NCTO][2];
        f32x4 bv[NCTO];
#pragma unroll
        for (int ct = 0; ct < NCTO; ++ct) {
          wo[ct][0] =
              *(const bf16x8*)(wb + 10240 + (ct * 2 + 0) * 512 + lane * 8);
          wo[ct][1] =
              *(const bf16x8*)(wb + 10240 + (ct * 2 + 1) * 512 + lane * 8);
          bv[ct] = *(const f32x4*)(bb + 192 + 16 * ct + 4 * q);
        }
#pragma unroll
        for (int rt = 0; rt < 4; ++rt) {
          const int mr = mf + rt * 16;
          const bf16x8 h0 =
              *(const bf16x8*)(Hc + ((mr * 128 + 16 * q) ^ ((mr & 7) << 4)));
          const bf16x8 h1 = *(const bf16x8*)(Hc + ((mr * 128 + 64 + 16 * q) ^
                                                   ((mr & 7) << 4)));
#pragma unroll
          for (int ct = 0; ct < NCTO; ++ct) {
            f32x4 aa = __builtin_amdgcn_mfma_f32_16x16x32_bf16(wo[ct][0], h0,
                                                               bv[ct], 0, 0, 0);
            aa = __builtin_amdgcn_mfma_f32_16x16x32_bf16(wo[ct][1], h1, aa, 0,
                                                         0, 0);
            uint2 u;
            u.x = pk2(aa.x, aa.y);
            u.y = pk2(aa.z, aa.w);
            *(uint2*)(Xc + ((mr * 64 + 32 * ct + 8 * q) ^ ((mr & 3) << 4))) = u;
          }
        }
      }

      // ---------- epilogue: thread reads row m's outputs, accumulates ------
      if constexpr (!FINAL) {
        float o[24];
#pragma unroll
        for (int j = 0; j < 3; ++j) {
          const bf16x8 v =
              *(const bf16x8*)(Xc + ((m * 64 + 16 * j) ^ ((m & 3) << 4)));
#pragma unroll
          for (int i = 0; i < 8; ++i) o[8 * j + i] = bf2f(v[i]);
        }
#pragma unroll
        for (int k = 0; k < kNLS; ++k) acc[k] += o[k] * wgt;
#pragma unroll
        for (int v = 0; v < kNLV; ++v) {
          const float cr = o[12 + v] * wgt, cn = o[18 + v] * wgt;
          acc[12 + v * 3 + 0] += cr * rhx + cn * nx;
          acc[12 + v * 3 + 1] += cr * rhy + cn * ny;
          acc[12 + v * 3 + 2] += cr * rhz + cn * nz;
        }
      } else {
        const bf16x8 v = *(const bf16x8*)(Xc + ((m * 64) ^ ((m & 3) << 4)));
        const float o0 = bf2f(v[0]), o1 = bf2f(v[1]), o2 = bf2f(v[2]);
        acc[0] += o0 * wgt;
        acc[1] += wgt * (o1 * rhx + o2 * nx);
        acc[2] += wgt * (o1 * rhy + o2 * ny);
        acc[3] += wgt * (o1 * rhz + o2 * nz);
      }
    }  // half
  }    // bs

  // ---------- block reduction ----------
#pragma unroll
  for (int k = 0; k < NACC; ++k) acc[k] = wred64(acc[k]);
  if (lane == 0) {
#pragma unroll
    for (int k = 0; k < NACC; ++k) red[wave * 32 + k] = acc[k];
  }
  __syncthreads();
  if (tid < NACC) {
    float sum = 0.f;
#pragma unroll
    for (int w = 0; w < 4; ++w) sum += red[w * 32 + tid];
    if constexpr (!FINAL) {
      if (tid < kNLS)
        scal_out[t * kNLS + tid] = sum;
      else
        vecs_out[t * 18 + (tid - kNLS)] = sum;
    } else {
      const float o =
          (tid == 0) ? (calib[0] * sum + calib[1]) : (calib[2] * sum);
      out4[t * 4 + tid] = o;
    }
  }
}

extern "C" void kernel_launch(void* const* d_in, const int* in_sizes, int n_in,
                              void* d_out, int out_size, void* d_ws,
                              size_t ws_size, hipStream_t stream) {
  const float* pred = (const float*)d_in[0];
  const float* cent = (const float*)d_in[1];
  const float* normals = (const float*)d_in[2];
  const float* areas = (const float*)d_in[3];
  const float* refl = (const float*)d_in[4];
  const float* cW1 = (const float*)d_in[5];
  const float* cb1 = (const float*)d_in[6];
  const float* cW2 = (const float*)d_in[7];
  const float* cb2 = (const float*)d_in[8];
  const float* cW3 = (const float*)d_in[9];
  const float* cb3 = (const float*)d_in[10];
  const float* cWo = (const float*)d_in[11];
  const float* cbo = (const float*)d_in[12];
  const float* fW1 = (const float*)d_in[13];
  const float* fb1 = (const float*)d_in[14];
  const float* fW2 = (const float*)d_in[15];
  const float* fb2 = (const float*)d_in[16];
  const float* fW3 = (const float*)d_in[17];
  const float* fb3 = (const float*)d_in[18];
  const float* fWo = (const float*)d_in[19];
  const float* fbo = (const float*)d_in[20];
  const float* calib = (const float*)d_in[21];

  float* ws = (float*)d_ws;
  float* nrmp = ws;                   // 3072
  float* scalA = nrmp + 3072;         // 12288
  float* vecsA = scalA + 12288;       // 18432
  float* scalB = vecsA + 18432;       // 12288
  float* vecsB = scalB + 12288;       // 18432
  float* BLs = vecsB + 18432;         // 12 * 224 = 2688
  short* WLs = (short*)(BLs + 2688);  // 12 * 12288 bf16
  float* outp = (float*)d_out;

  prep_nrm<<<4, 256, 0, stream>>>(normals, nrmp);

  // weights -> frag layout (c-MLPs are mlp 0..7, f-MLPs are 8..11)
  prep_w<29, 64, 32, 64><<<8, 256, 0, stream>>>(cW1, WLs, 0, 8, 0);
  prep_w<64, 64, 64, 64><<<16, 256, 0, stream>>>(cW2, WLs, 2048, 8, 0);
  prep_w<64, 64, 64, 64><<<16, 256, 0, stream>>>(cW3, WLs, 6144, 8, 0);
  prep_w<64, 24, 64, 32><<<8, 256, 0, stream>>>(cWo, WLs, 10240, 8, 0);
  prep_w<29, 64, 32, 64><<<4, 256, 0, stream>>>(fW1, WLs, 0, 4, 8);
  prep_w<64, 64, 64, 64><<<8, 256, 0, stream>>>(fW2, WLs, 2048, 4, 8);
  prep_w<64, 64, 64, 64><<<8, 256, 0, stream>>>(fW3, WLs, 6144, 4, 8);
  prep_w<64, 3, 64, 32><<<4, 256, 0, stream>>>(fWo, WLs, 10240, 4, 8);

  prep_b<<<2, 256, 0, stream>>>(cb1, BLs, 8, 64, 64, 0, 0);
  prep_b<<<2, 256, 0, stream>>>(cb2, BLs, 8, 64, 64, 64, 0);
  prep_b<<<2, 256, 0, stream>>>(cb3, BLs, 8, 64, 64, 128, 0);
  prep_b<<<1, 256, 0, stream>>>(cbo, BLs, 8, 24, 32, 192, 0);
  prep_b<<<1, 256, 0, stream>>>(fb1, BLs, 4, 64, 64, 0, 8);
  prep_b<<<1, 256, 0, stream>>>(fb2, BLs, 4, 64, 64, 64, 8);
  prep_b<<<1, 256, 0, stream>>>(fb3, BLs, 4, 64, 64, 128, 8);
  prep_b<<<1, 256, 0, stream>>>(fbo, BLs, 4, 3, 32, 192, 8);

  mlp_main<true, false><<<kNTGT, 256, 0, stream>>>(
      cent, cent, nrmp, areas, refl, WLs, BLs, 0, nullptr, nullptr, scalA,
      vecsA, nullptr, nullptr);
  mlp_main<false, false><<<kNTGT, 256, 0, stream>>>(
      cent, cent, nrmp, areas, refl, WLs, BLs, 4, scalA, vecsA, scalB, vecsB,
      nullptr, nullptr);
  mlp_main<false, true><<<kNPTS, 256, 0, stream>>>(
      pred, cent, nrmp, areas, refl, WLs, BLs, 8, scalB, vecsB, nullptr,
      nullptr, calib, outp);
}